// Round 11
// baseline (342.109 us; speedup 1.0000x reference)
//
#include <hip/hip_runtime.h>
#include <hip/hip_bf16.h>

#define CDIM 32
#define KCLS 20
#define NBASE 12
#define PPROP 1024
#define TBLW 20   // 18 sem cols (2..19) + binary + count (fallback path)
#define PKW 24    // packed row: 24 shorts = 48B (18 sem bf16, bin bf16, 5 pad)
#define SLOTS 3072  // per-proposal bucket capacity (mean 1953, +25 sigma)

typedef __attribute__((ext_vector_type(8))) short bf16x8;
typedef __attribute__((ext_vector_type(4))) float f32x4;

__device__ __forceinline__ void lds_addf(float* p, float v) {
  __hip_atomic_fetch_add(p, v, __ATOMIC_RELAXED, __HIP_MEMORY_SCOPE_WORKGROUP);
}
__device__ __forceinline__ int lds_addi(int* p, int v) {
  return __hip_atomic_fetch_add(p, v, __ATOMIC_RELAXED, __HIP_MEMORY_SCOPE_WORKGROUP);
}
__device__ __forceinline__ void glb_addf(float* p, float v) {
  __hip_atomic_fetch_add(p, v, __ATOMIC_RELAXED, __HIP_MEMORY_SCOPE_AGENT);
}
__device__ __forceinline__ int glb_addi(int* p, int v) {
  return __hip_atomic_fetch_add(p, v, __ATOMIC_RELAXED, __HIP_MEMORY_SCOPE_AGENT);
}

// f32 -> bf16 (round-to-nearest-even), bit pattern in a short
__device__ __forceinline__ short f2bf(float x) {
  unsigned u = __builtin_bit_cast(unsigned, x);
  unsigned r = (u + 0x7fffu + ((u >> 16) & 1u)) >> 16;
  return (short)r;
}
__device__ __forceinline__ unsigned pk2(float lo, float hi) {
  return (unsigned)(unsigned short)f2bf(lo) | ((unsigned)(unsigned short)f2bf(hi) << 16);
}
__device__ __forceinline__ float bflo(unsigned u) {
  return __builtin_bit_cast(float, u << 16);
}
__device__ __forceinline__ float bfhi(unsigned u) {
  return __builtin_bit_cast(float, u & 0xffff0000u);
}

// DPP add step; ctrl immediate via template (round-5 lesson)
template <int CTRL>
__device__ __forceinline__ float dpp_add(float x) {
  int s = __builtin_amdgcn_update_dpp(0, __builtin_bit_cast(int, x),
                                      CTRL, 0xf, 0xf, true);
  return x + __builtin_bit_cast(float, s);
}
// sum across each 16-lane DPP row -> lanes 15/31/47/63 hold the row total
__device__ __forceinline__ float red16(float x) {
  x = dpp_add<0x111>(x);  // row_shr:1
  x = dpp_add<0x112>(x);  // row_shr:2
  x = dpp_add<0x114>(x);  // row_shr:4
  x = dpp_add<0x118>(x);  // row_shr:8
  return x;
}
// full-wave sum -> lane 63
__device__ __forceinline__ float red64(float x) {
  x = red16(x);
  x = dpp_add<0x142>(x);  // row_bcast:15
  x = dpp_add<0x143>(x);  // row_bcast:31
  return x;
}

// B-frag for mfma_f32_16x16x32_bf16 from row-major [K=32][N=32] weight matrix.
__device__ __forceinline__ bf16x8 make_bfrag(const float* __restrict__ W,
                                             int lane, int colOff) {
  int n = (lane & 15) + colOff;
  int kb = (lane >> 4) * 8;
  bf16x8 b;
#pragma unroll
  for (int e = 0; e < 8; e++) b[e] = f2bf(W[(kb + e) * CDIM + n]);
  return b;
}

// ---------------- zero workspace accumulators (replaces hipMemsetAsync node) -------
__global__ void k_zero(float* __restrict__ head, int nfloats, int* __restrict__ cnt) {
  int t = blockIdx.x * blockDim.x + threadIdx.x;
  int stride = gridDim.x * blockDim.x;
  for (int i = t; i < nfloats; i += stride) head[i] = 0.f;
  for (int i = t; i < PPROP; i += stride) cnt[i] = 0;
}

// ---------------- scores + bf16 row packing for the proposal gather ----------------
__global__ void k_scores(const float* __restrict__ sem, const float* __restrict__ bin,
                         float* __restrict__ out, int4* __restrict__ packed, int n) {
  int stride = gridDim.x * blockDim.x;
  for (int i = blockIdx.x * blockDim.x + threadIdx.x; i < n; i += stride) {
    const float4* r = reinterpret_cast<const float4*>(sem + (size_t)i * KCLS);
    float s[KCLS];
    float4 v;
    v = r[0]; s[0]=v.x; s[1]=v.y; s[2]=v.z; s[3]=v.w;
    v = r[1]; s[4]=v.x; s[5]=v.y; s[6]=v.z; s[7]=v.w;
    v = r[2]; s[8]=v.x; s[9]=v.y; s[10]=v.z; s[11]=v.w;
    v = r[3]; s[12]=v.x; s[13]=v.y; s[14]=v.z; s[15]=v.w;
    v = r[4]; s[16]=v.x; s[17]=v.y; s[18]=v.z; s[19]=v.w;
    float bv = bin[i];

    if (packed) {
      int4 p0, p1, p2;
      p0.x = pk2(s[2],  s[3]);  p0.y = pk2(s[4],  s[5]);
      p0.z = pk2(s[6],  s[7]);  p0.w = pk2(s[8],  s[9]);
      p1.x = pk2(s[10], s[11]); p1.y = pk2(s[12], s[13]);
      p1.z = pk2(s[14], s[15]); p1.w = pk2(s[16], s[17]);
      p2.x = pk2(s[18], s[19]); p2.y = pk2(bv, 0.f);
      p2.z = 0; p2.w = 0;
      int4* pr = packed + (size_t)i * 3;
      pr[0] = p0; pr[1] = p1; pr[2] = p2;
    }

    float m12 = s[0];
#pragma unroll
    for (int k = 1; k < NBASE; k++) m12 = fmaxf(m12, s[k]);
    float sum12 = 0.f;
#pragma unroll
    for (int k = 0; k < NBASE; k++) { s[k] = __expf(s[k] - m12); sum12 += s[k]; }

    float m8 = s[NBASE];
#pragma unroll
    for (int k = NBASE + 1; k < KCLS; k++) m8 = fmaxf(m8, s[k]);
    float sum8 = 0.f;
#pragma unroll
    for (int k = NBASE; k < KCLS; k++) { s[k] = __expf(s[k] - m8); sum8 += s[k]; }

    float sig = 1.f / (1.f + __expf(-bv));
    // analytic: renormalization denominator == 1, fold gate/softmax-denoms
    float cb = sig / sum12;
    float cn = (1.f - sig) / sum8;
#pragma unroll
    for (int k = 0; k < NBASE; k++) s[k] *= cb;
#pragma unroll
    for (int k = NBASE; k < KCLS; k++) s[k] *= cn;

    float4* o = reinterpret_cast<float4*>(out + (size_t)i * KCLS);
    o[0] = make_float4(s[0], s[1], s[2], s[3]);
    o[1] = make_float4(s[4], s[5], s[6], s[7]);
    o[2] = make_float4(s[8], s[9], s[10], s[11]);
    o[3] = make_float4(s[12], s[13], s[14], s[15]);
    o[4] = make_float4(s[16], s[17], s[18], s[19]);
  }
}

// ---------------- group memberships by proposal (counting sort) ----------------
// Rounds 7-9 lesson: 40M scattered LDS atomic f32 adds were the wall. Here:
// 1 LDS atomic per membership + ~1K global atomics per block; values never gathered.
__global__ __launch_bounds__(512) void k_group(const int* __restrict__ pidx,
    const int* __restrict__ pid, int* __restrict__ cnt, int* __restrict__ bucket,
    int m) {
  __shared__ int hist[PPROP];
  __shared__ int bs[PPROP];
  int t = threadIdx.x;
  for (int j = t; j < PPROP; j += 512) hist[j] = 0;
  __syncthreads();

  int base = blockIdx.x * 4096;
  int p[8], q[8], lr[8];
#pragma unroll
  for (int j = 0; j < 8; j++) {
    int i = base + j * 512 + t;
    if (i < m) {
      p[j] = pid[i];
      q[j] = pidx[i];
      lr[j] = lds_addi(&hist[p[j]], 1);
    } else {
      p[j] = -1; q[j] = 0; lr[j] = 0;
    }
  }
  __syncthreads();
  for (int j = t; j < PPROP; j += 512) {
    int h = hist[j];
    bs[j] = h ? glb_addi(&cnt[j], h) : 0;
  }
  __syncthreads();
#pragma unroll
  for (int j = 0; j < 8; j++) {
    if (p[j] >= 0) {
      int pos = bs[p[j]] + lr[j];
      if (pos < SLOTS) bucket[(size_t)p[j] * SLOTS + pos] = q[j];
    }
  }
}

// ---------------- per-proposal mean via register accumulation (zero atomics) -------
// 512 threads = 8 waves/block, 1024 blocks -> 32 waves/CU of in-flight gathers.
__global__ __launch_bounds__(512) void k_psum(const int4* __restrict__ packed,
    const int* __restrict__ cnt, const int* __restrict__ bucket,
    float* __restrict__ psem, float* __restrict__ pbin) {
  __shared__ float wacc[8 * 19];
  int p = blockIdx.x;
  int t = threadIdx.x;
  int c = cnt[p];
  int cc = c < SLOTS ? c : SLOTS;

  float s[19];
#pragma unroll
  for (int k = 0; k < 19; k++) s[k] = 0.f;

  const int* bk = bucket + (size_t)p * SLOTS;
  for (int j = t; j < cc; j += 512) {
    int q = bk[j];
    const int4* r = packed + (size_t)q * 3;
    int4 a = r[0], b = r[1], cw = r[2];
    s[0] += bflo(a.x);  s[1] += bfhi(a.x);
    s[2] += bflo(a.y);  s[3] += bfhi(a.y);
    s[4] += bflo(a.z);  s[5] += bfhi(a.z);
    s[6] += bflo(a.w);  s[7] += bfhi(a.w);
    s[8] += bflo(b.x);  s[9] += bfhi(b.x);
    s[10] += bflo(b.y); s[11] += bfhi(b.y);
    s[12] += bflo(b.z); s[13] += bfhi(b.z);
    s[14] += bflo(b.w); s[15] += bfhi(b.w);
    s[16] += bflo(cw.x); s[17] += bfhi(cw.x);
    s[18] += bflo(cw.y);
  }

  int lane = t & 63, w = t >> 6;
#pragma unroll
  for (int k = 0; k < 19; k++) s[k] = red64(s[k]);
  if (lane == 63) {
#pragma unroll
    for (int k = 0; k < 19; k++) wacc[w * 19 + k] = s[k];
  }
  __syncthreads();
  if (t < 19) {
    float v = 0.f;
#pragma unroll
    for (int w2 = 0; w2 < 8; w2++) v += wacc[w2 * 19 + t];
    float inv = 1.f / fmaxf((float)c, 1.f);
    if (t < 18) psem[p * 18 + t] = v * inv;
    else pbin[p] = v * inv;
  }
}

// ---------------- fallback: packed-row LDS scatter (round-9 path) ----------------
__global__ __launch_bounds__(512) void k_scatter_p(const int4* __restrict__ packed,
    const int* __restrict__ pidx, const int* __restrict__ pid,
    float* __restrict__ acc, int m) {
  __shared__ float tbl[PPROP * TBLW];
  for (int t = threadIdx.x; t < PPROP * TBLW; t += blockDim.x) tbl[t] = 0.f;
  __syncthreads();
  int stride = gridDim.x * blockDim.x;
  for (int i = blockIdx.x * blockDim.x + threadIdx.x; i < m; i += stride) {
    int q = pidx[i];
    int p = pid[i];
    const int4* r = packed + (size_t)q * 3;
    int4 a = r[0], b = r[1], c = r[2];
    float* t = tbl + p * TBLW;
    lds_addf(t + 0, bflo(a.x)); lds_addf(t + 1, bfhi(a.x));
    lds_addf(t + 2, bflo(a.y)); lds_addf(t + 3, bfhi(a.y));
    lds_addf(t + 4, bflo(a.z)); lds_addf(t + 5, bfhi(a.z));
    lds_addf(t + 6, bflo(a.w)); lds_addf(t + 7, bfhi(a.w));
    lds_addf(t + 8, bflo(b.x)); lds_addf(t + 9, bfhi(b.x));
    lds_addf(t +10, bflo(b.y)); lds_addf(t +11, bfhi(b.y));
    lds_addf(t +12, bflo(b.z)); lds_addf(t +13, bfhi(b.z));
    lds_addf(t +14, bflo(b.w)); lds_addf(t +15, bfhi(b.w));
    lds_addf(t +16, bflo(c.x)); lds_addf(t +17, bfhi(c.x));
    lds_addf(t +18, bflo(c.y));
    lds_addf(t +19, 1.f);
  }
  __syncthreads();
  for (int t = threadIdx.x; t < PPROP * TBLW; t += blockDim.x) {
    float v = tbl[t];
    if (v != 0.f) glb_addf(acc + t, v);
  }
}

// ---------------- fallback: f32 gather scatter (if ws too small for packed) --------
__global__ __launch_bounds__(512) void k_scatter(const float* __restrict__ sem,
    const float* __restrict__ bin, const int* __restrict__ pidx,
    const int* __restrict__ pid, float* __restrict__ acc, int m) {
  __shared__ float tbl[PPROP * TBLW];
  for (int t = threadIdx.x; t < PPROP * TBLW; t += blockDim.x) tbl[t] = 0.f;
  __syncthreads();
  int stride = gridDim.x * blockDim.x;
  for (int i = blockIdx.x * blockDim.x + threadIdx.x; i < m; i += stride) {
    int q = pidx[i];
    int p = pid[i];
    const float* row = sem + (size_t)q * KCLS;
    float2 a  = *reinterpret_cast<const float2*>(row + 2);
    float4 c0 = *reinterpret_cast<const float4*>(row + 4);
    float4 c1 = *reinterpret_cast<const float4*>(row + 8);
    float4 c2 = *reinterpret_cast<const float4*>(row + 12);
    float4 c3 = *reinterpret_cast<const float4*>(row + 16);
    float bv = bin[q];
    float* t = tbl + p * TBLW;
    lds_addf(t + 0, a.x);  lds_addf(t + 1, a.y);
    lds_addf(t + 2, c0.x); lds_addf(t + 3, c0.y); lds_addf(t + 4, c0.z); lds_addf(t + 5, c0.w);
    lds_addf(t + 6, c1.x); lds_addf(t + 7, c1.y); lds_addf(t + 8, c1.z); lds_addf(t + 9, c1.w);
    lds_addf(t +10, c2.x); lds_addf(t +11, c2.y); lds_addf(t +12, c2.z); lds_addf(t +13, c2.w);
    lds_addf(t +14, c3.x); lds_addf(t +15, c3.y); lds_addf(t +16, c3.z); lds_addf(t +17, c3.w);
    lds_addf(t +18, bv);
    lds_addf(t +19, 1.f);
  }
  __syncthreads();
  for (int t = threadIdx.x; t < PPROP * TBLW; t += blockDim.x) {
    float v = tbl[t];
    if (v != 0.f) glb_addf(acc + t, v);
  }
}

// ---------------- finalize proposal means (fallback paths only) ----------------
__global__ void k_finalize(const float* __restrict__ acc,
                           float* __restrict__ psem, float* __restrict__ pbin) {
  int p = blockIdx.x * blockDim.x + threadIdx.x;
  if (p < PPROP) {
    const float* t = acc + p * TBLW;
    float cnt = fmaxf(t[19], 1.f);
    float r = 1.f / cnt;
#pragma unroll
    for (int c = 0; c < 18; c++) psem[p * 18 + c] = t[c] * r;
    pbin[p] = t[18] * r;
  }
}

// ---------------- heads via MFMA: mask, iou, BN stats over h1=f@W1 ----------------
__global__ __launch_bounds__(256, 4) void k_heads_m(const float* __restrict__ feats,
    const float* __restrict__ W1,
    const float* __restrict__ Wm1, const float* __restrict__ bm1,
    const float* __restrict__ Wm2, const float* __restrict__ bm2,
    const float* __restrict__ Wi,  const float* __restrict__ bi,
    float* __restrict__ mask_out, float* __restrict__ iou_out,
    float* __restrict__ stats, int n) {
  __shared__ float red[64];  // S[32], Q[32]
  int t = threadIdx.x;
  int lane = t & 63;
  int nn = lane & 15;
  int grp = lane >> 4;

  bf16x8 bWm0 = make_bfrag(Wm1, lane, 0);
  bf16x8 bWm1f = make_bfrag(Wm1, lane, 16);
  bf16x8 bW10 = make_bfrag(W1, lane, 0);
  bf16x8 bW11 = make_bfrag(W1, lane, 16);
  bf16x8 bWi;
  {
    int kb = grp * 8;
#pragma unroll
    for (int e = 0; e < 8; e++) bWi[e] = (nn == 0) ? f2bf(Wi[kb + e]) : (short)0;
  }
  float bm1a = bm1[nn], bm1b = bm1[nn + 16];
  float wm2a = Wm2[nn], wm2b = Wm2[nn + 16];
  float bm2v = bm2[0], biv = bi[0];

  float hs0 = 0.f, hs1 = 0.f, hq0 = 0.f, hq1 = 0.f;

  int wave   = (blockIdx.x * blockDim.x + t) >> 6;
  int nwaves = (gridDim.x * blockDim.x) >> 6;
  int ntiles = (n + 15) >> 4;

  for (int tile = wave; tile < ntiles; tile += nwaves) {
    int p0 = tile << 4;
    int row = p0 + nn;
    bool rv = row < n;
    const float4* fr = reinterpret_cast<const float4*>(
        feats + (size_t)(rv ? row : (n - 1)) * CDIM + grp * 8);
    float4 v0 = fr[0], v1 = fr[1];
    bf16x8 a;
    if (rv) {
      a[0] = f2bf(v0.x); a[1] = f2bf(v0.y); a[2] = f2bf(v0.z); a[3] = f2bf(v0.w);
      a[4] = f2bf(v1.x); a[5] = f2bf(v1.y); a[6] = f2bf(v1.z); a[7] = f2bf(v1.w);
    } else {
#pragma unroll
      for (int e = 0; e < 8; e++) a[e] = 0;
    }

    f32x4 am0, am1, ah0, ah1, ai;
#pragma unroll
    for (int r = 0; r < 4; r++) { am0[r] = bm1a; am1[r] = bm1b; ah0[r] = 0.f; ah1[r] = 0.f; ai[r] = 0.f; }

    am0 = __builtin_amdgcn_mfma_f32_16x16x32_bf16(a, bWm0,  am0, 0, 0, 0);
    am1 = __builtin_amdgcn_mfma_f32_16x16x32_bf16(a, bWm1f, am1, 0, 0, 0);
    ah0 = __builtin_amdgcn_mfma_f32_16x16x32_bf16(a, bW10,  ah0, 0, 0, 0);
    ah1 = __builtin_amdgcn_mfma_f32_16x16x32_bf16(a, bW11,  ah1, 0, 0, 0);
    ai  = __builtin_amdgcn_mfma_f32_16x16x32_bf16(a, bWi,   ai,  0, 0, 0);

    float t0 = fmaxf(am0[0], 0.f) * wm2a + fmaxf(am1[0], 0.f) * wm2b;
    float t1 = fmaxf(am0[1], 0.f) * wm2a + fmaxf(am1[1], 0.f) * wm2b;
    float t2 = fmaxf(am0[2], 0.f) * wm2a + fmaxf(am1[2], 0.f) * wm2b;
    float t3 = fmaxf(am0[3], 0.f) * wm2a + fmaxf(am1[3], 0.f) * wm2b;
    t0 = red16(t0); t1 = red16(t1); t2 = red16(t2); t3 = red16(t3);

    if (p0 + 16 <= n) {
      if (nn == 15) {
        *reinterpret_cast<float4*>(mask_out + p0 + grp * 4) =
            make_float4(t0 + bm2v, t1 + bm2v, t2 + bm2v, t3 + bm2v);
      }
      if (nn == 0) {
        *reinterpret_cast<float4*>(iou_out + p0 + grp * 4) =
            make_float4(ai[0] + biv, ai[1] + biv, ai[2] + biv, ai[3] + biv);
      }
    } else {
      if (nn == 15) {
        float tv[4] = {t0, t1, t2, t3};
#pragma unroll
        for (int r = 0; r < 4; r++) {
          int p = p0 + grp * 4 + r;
          if (p < n) mask_out[p] = tv[r] + bm2v;
        }
      }
      if (nn == 0) {
#pragma unroll
        for (int r = 0; r < 4; r++) {
          int p = p0 + grp * 4 + r;
          if (p < n) iou_out[p] = ai[r] + biv;
        }
      }
    }

#pragma unroll
    for (int r = 0; r < 4; r++) {
      hs0 += ah0[r]; hq0 = fmaf(ah0[r], ah0[r], hq0);
      hs1 += ah1[r]; hq1 = fmaf(ah1[r], ah1[r], hq1);
    }
  }

  __syncthreads();
  for (int q = t; q < 64; q += blockDim.x) red[q] = 0.f;
  __syncthreads();
  lds_addf(&red[nn], hs0);       lds_addf(&red[nn + 16], hs1);
  lds_addf(&red[32 + nn], hq0);  lds_addf(&red[48 + nn], hq1);
  __syncthreads();
  for (int q = t; q < 64; q += blockDim.x) glb_addf(&stats[q], red[q]);
}

// ---------------- pt_offsets via MFMA, BN prep inlined ----------------
// stats hold S=sum(f@W1), Q=sum((f@W1)^2); var shift-invariant so b1 cancels;
// tc = be1 - mean*sc makes (h_noBias*sc + tc) == BN(h_full). (bnprep kernel folded.)
__global__ __launch_bounds__(256, 4) void k_offsets_m(const float* __restrict__ feats,
    const float* __restrict__ W1,
    const float* __restrict__ W2, const float* __restrict__ b2,
    const float* __restrict__ stats, const float* __restrict__ g1,
    const float* __restrict__ be1, float* __restrict__ out_off, int n, float invN) {
  int t = threadIdx.x;
  int lane = t & 63;
  int nn = lane & 15;
  int grp = lane >> 4;

  bf16x8 bW10 = make_bfrag(W1, lane, 0);
  bf16x8 bW11 = make_bfrag(W1, lane, 16);
  float scA, tcA, scB, tcB;
  {
    float meanA = stats[nn] * invN;
    float varA  = stats[CDIM + nn] * invN - meanA * meanA;
    scA = g1[nn] * rsqrtf(varA + 1e-4f);
    tcA = be1[nn] - meanA * scA;
    float meanB = stats[nn + 16] * invN;
    float varB  = stats[CDIM + nn + 16] * invN - meanB * meanB;
    scB = g1[nn + 16] * rsqrtf(varB + 1e-4f);
    tcB = be1[nn + 16] - meanB * scB;
  }
  float wxA = W2[nn * 3 + 0], wxB = W2[(nn + 16) * 3 + 0];
  float wyA = W2[nn * 3 + 1], wyB = W2[(nn + 16) * 3 + 1];
  float wzA = W2[nn * 3 + 2], wzB = W2[(nn + 16) * 3 + 2];
  float b2x = b2[0], b2y = b2[1], b2z = b2[2];

  int wave   = (blockIdx.x * blockDim.x + t) >> 6;
  int nwaves = (gridDim.x * blockDim.x) >> 6;
  int ntiles = (n + 15) >> 4;

  for (int tile = wave; tile < ntiles; tile += nwaves) {
    int p0 = tile << 4;
    int row = p0 + nn;
    bool rv = row < n;
    const float4* fr = reinterpret_cast<const float4*>(
        feats + (size_t)(rv ? row : (n - 1)) * CDIM + grp * 8);
    float4 v0 = fr[0], v1 = fr[1];
    bf16x8 a;
    if (rv) {
      a[0] = f2bf(v0.x); a[1] = f2bf(v0.y); a[2] = f2bf(v0.z); a[3] = f2bf(v0.w);
      a[4] = f2bf(v1.x); a[5] = f2bf(v1.y); a[6] = f2bf(v1.z); a[7] = f2bf(v1.w);
    } else {
#pragma unroll
      for (int e = 0; e < 8; e++) a[e] = 0;
    }

    f32x4 ah0 = {0.f, 0.f, 0.f, 0.f}, ah1 = {0.f, 0.f, 0.f, 0.f};
    ah0 = __builtin_amdgcn_mfma_f32_16x16x32_bf16(a, bW10, ah0, 0, 0, 0);
    ah1 = __builtin_amdgcn_mfma_f32_16x16x32_bf16(a, bW11, ah1, 0, 0, 0);

    float tx[4], ty[4], tz[4];
#pragma unroll
    for (int r = 0; r < 4; r++) {
      float y0 = fmaxf(fmaf(ah0[r], scA, tcA), 0.f);
      float y1 = fmaxf(fmaf(ah1[r], scB, tcB), 0.f);
      tx[r] = red16(y0 * wxA + y1 * wxB);
      ty[r] = red16(y0 * wyA + y1 * wyB);
      tz[r] = red16(y0 * wzA + y1 * wzB);
    }

    if (nn == 15) {
      int pbase = p0 + grp * 4;
      if (pbase + 4 <= n) {
        float4* o = reinterpret_cast<float4*>(out_off + (size_t)pbase * 3);
        o[0] = make_float4(tx[0] + b2x, ty[0] + b2y, tz[0] + b2z, tx[1] + b2x);
        o[1] = make_float4(ty[1] + b2y, tz[1] + b2z, tx[2] + b2x, ty[2] + b2y);
        o[2] = make_float4(tz[2] + b2z, tx[3] + b2x, ty[3] + b2y, tz[3] + b2z);
      } else {
#pragma unroll
        for (int r = 0; r < 4; r++) {
          int p = pbase + r;
          if (p < n) {
            out_off[(size_t)p * 3 + 0] = tx[r] + b2x;
            out_off[(size_t)p * 3 + 1] = ty[r] + b2y;
            out_off[(size_t)p * 3 + 2] = tz[r] + b2z;
          }
        }
      }
    }
  }
}

extern "C" void kernel_launch(void* const* d_in, const int* in_sizes, int n_in,
                              void* d_out, int out_size, void* d_ws, size_t ws_size,
                              hipStream_t stream) {
  const float* feats = (const float*)d_in[0];
  const float* sem   = (const float*)d_in[1];
  const float* bin   = (const float*)d_in[2];
  const int*   pidx  = (const int*)d_in[3];
  const int*   pid   = (const int*)d_in[4];
  const float* W1  = (const float*)d_in[5];
  // b1 (d_in[6]) cancels analytically: BN var is shift-invariant, mean shift folds
  const float* g1  = (const float*)d_in[7];
  const float* be1 = (const float*)d_in[8];
  const float* W2  = (const float*)d_in[9];
  const float* b2  = (const float*)d_in[10];
  const float* Wm1 = (const float*)d_in[11];
  const float* bm1 = (const float*)d_in[12];
  const float* Wm2 = (const float*)d_in[13];
  const float* bm2 = (const float*)d_in[14];
  const float* Wi  = (const float*)d_in[15];
  const float* bi  = (const float*)d_in[16];

  int n = in_sizes[2];   // binary_scores is (N,1)
  int m = in_sizes[3];   // memberships

  float* out = (float*)d_out;
  float* o_scores = out;
  float* o_off  = out + (size_t)n * KCLS;
  float* o_psem = o_off + (size_t)n * 3;
  float* o_pbin = o_psem + (size_t)PPROP * 18;
  float* o_mask = o_pbin + PPROP;
  float* o_iou  = o_mask + n;

  char* wsb = (char*)d_ws;
  float* stats = (float*)wsb;               // 64 floats: S[32], Q[32]
  float* acc   = stats + 2 * CDIM;          // P*TBLW floats (fallback paths)
  size_t head_floats = 2 * CDIM + PPROP * TBLW;
  int* cnt = (int*)(wsb + head_floats * sizeof(float));   // 1024 ints
  size_t pk_off = (head_floats * sizeof(float) + PPROP * sizeof(int) + 15) & ~(size_t)15;
  size_t pk_bytes = (size_t)n * PKW * sizeof(short);      // 16B multiple
  size_t bk_off = pk_off + pk_bytes;
  size_t bk_bytes = (size_t)PPROP * SLOTS * sizeof(int);
  bool use_packed  = (pk_off + pk_bytes) <= ws_size;
  bool use_grouped = use_packed && (bk_off + bk_bytes) <= ws_size;
  int4* packed = use_packed ? (int4*)(wsb + pk_off) : nullptr;
  int* bucket  = (int*)(wsb + bk_off);

  // zero accumulators via kernel (round-10: fillBufferAligned dispatches showed
  // ~146us anomalies; a plain kernel zero is a few us and profiles under our name)
  k_zero   <<<32, 256, 0, stream>>>(stats, (int)head_floats, cnt);

  k_scores <<<2048, 256, 0, stream>>>(sem, bin, o_scores, packed, n);
  if (use_grouped) {
    int nb = (m + 4095) / 4096;
    k_group<<<nb, 512, 0, stream>>>(pidx, pid, cnt, bucket, m);
    k_psum <<<PPROP, 512, 0, stream>>>(packed, cnt, bucket, o_psem, o_pbin);
  } else if (use_packed) {
    k_scatter_p<<<512, 512, 0, stream>>>(packed, pidx, pid, acc, m);
    k_finalize<<<4, 256, 0, stream>>>(acc, o_psem, o_pbin);
  } else {
    k_scatter <<<512, 512, 0, stream>>>(sem, bin, pidx, pid, acc, m);
    k_finalize<<<4, 256, 0, stream>>>(acc, o_psem, o_pbin);
  }
  k_heads_m <<<2048, 256, 0, stream>>>(feats, W1, Wm1, bm1, Wm2, bm2, Wi, bi,
                                       o_mask, o_iou, stats, n);
  k_offsets_m<<<2048, 256, 0, stream>>>(feats, W1, W2, b2, stats, g1, be1,
                                        o_off, n, 1.0f / (float)n);
}

// Round 12
// 319.317 us; speedup vs baseline: 1.0714x; 1.0714x over previous
//
#include <hip/hip_runtime.h>
#include <hip/hip_bf16.h>

#define CDIM 32
#define KCLS 20
#define NBASE 12
#define PPROP 1024
#define TBLW 20   // 18 sem cols (2..19) + binary + count (fallback path)
#define PKW 24    // packed row: 24 shorts = 48B (18 sem bf16, bin bf16, 5 pad)
#define SLOTS 3072  // per-proposal bucket capacity (mean 1953, +25 sigma)

typedef __attribute__((ext_vector_type(8))) short bf16x8;
typedef __attribute__((ext_vector_type(4))) float f32x4;

__device__ __forceinline__ void lds_addf(float* p, float v) {
  __hip_atomic_fetch_add(p, v, __ATOMIC_RELAXED, __HIP_MEMORY_SCOPE_WORKGROUP);
}
__device__ __forceinline__ int lds_addi(int* p, int v) {
  return __hip_atomic_fetch_add(p, v, __ATOMIC_RELAXED, __HIP_MEMORY_SCOPE_WORKGROUP);
}
__device__ __forceinline__ void glb_addf(float* p, float v) {
  __hip_atomic_fetch_add(p, v, __ATOMIC_RELAXED, __HIP_MEMORY_SCOPE_AGENT);
}
__device__ __forceinline__ int glb_addi(int* p, int v) {
  return __hip_atomic_fetch_add(p, v, __ATOMIC_RELAXED, __HIP_MEMORY_SCOPE_AGENT);
}

__device__ __forceinline__ short f2bf(float x) {
  unsigned u = __builtin_bit_cast(unsigned, x);
  unsigned r = (u + 0x7fffu + ((u >> 16) & 1u)) >> 16;
  return (short)r;
}
__device__ __forceinline__ unsigned pk2(float lo, float hi) {
  return (unsigned)(unsigned short)f2bf(lo) | ((unsigned)(unsigned short)f2bf(hi) << 16);
}
__device__ __forceinline__ float bflo(unsigned u) {
  return __builtin_bit_cast(float, u << 16);
}
__device__ __forceinline__ float bfhi(unsigned u) {
  return __builtin_bit_cast(float, u & 0xffff0000u);
}

template <int CTRL>
__device__ __forceinline__ float dpp_add(float x) {
  int s = __builtin_amdgcn_update_dpp(0, __builtin_bit_cast(int, x),
                                      CTRL, 0xf, 0xf, true);
  return x + __builtin_bit_cast(float, s);
}
__device__ __forceinline__ float red16(float x) {
  x = dpp_add<0x111>(x);
  x = dpp_add<0x112>(x);
  x = dpp_add<0x114>(x);
  x = dpp_add<0x118>(x);
  return x;
}
__device__ __forceinline__ float red64(float x) {
  x = red16(x);
  x = dpp_add<0x142>(x);
  x = dpp_add<0x143>(x);
  return x;
}

__device__ __forceinline__ bf16x8 make_bfrag(const float* __restrict__ W,
                                             int lane, int colOff) {
  int n = (lane & 15) + colOff;
  int kb = (lane >> 4) * 8;
  bf16x8 b;
#pragma unroll
  for (int e = 0; e < 8; e++) b[e] = f2bf(W[(kb + e) * CDIM + n]);
  return b;
}

// ================= device bodies (shared between merged & fallback kernels) ======

// scores: open-vocab renorm softmax-gate + bf16 row packing. virtual grid vb/vgrid.
__device__ __forceinline__ void dev_scores(int vb, int vgrid,
    const float* __restrict__ sem, const float* __restrict__ bin,
    float* __restrict__ out, int4* __restrict__ packed, int n) {
  int stride = vgrid * 256;
  for (int i = vb * 256 + threadIdx.x; i < n; i += stride) {
    const float4* r = reinterpret_cast<const float4*>(sem + (size_t)i * KCLS);
    float s[KCLS];
    float4 v;
    v = r[0]; s[0]=v.x; s[1]=v.y; s[2]=v.z; s[3]=v.w;
    v = r[1]; s[4]=v.x; s[5]=v.y; s[6]=v.z; s[7]=v.w;
    v = r[2]; s[8]=v.x; s[9]=v.y; s[10]=v.z; s[11]=v.w;
    v = r[3]; s[12]=v.x; s[13]=v.y; s[14]=v.z; s[15]=v.w;
    v = r[4]; s[16]=v.x; s[17]=v.y; s[18]=v.z; s[19]=v.w;
    float bv = bin[i];

    if (packed) {
      int4 p0, p1, p2;
      p0.x = pk2(s[2],  s[3]);  p0.y = pk2(s[4],  s[5]);
      p0.z = pk2(s[6],  s[7]);  p0.w = pk2(s[8],  s[9]);
      p1.x = pk2(s[10], s[11]); p1.y = pk2(s[12], s[13]);
      p1.z = pk2(s[14], s[15]); p1.w = pk2(s[16], s[17]);
      p2.x = pk2(s[18], s[19]); p2.y = pk2(bv, 0.f);
      p2.z = 0; p2.w = 0;
      int4* pr = packed + (size_t)i * 3;
      pr[0] = p0; pr[1] = p1; pr[2] = p2;
    }

    float m12 = s[0];
#pragma unroll
    for (int k = 1; k < NBASE; k++) m12 = fmaxf(m12, s[k]);
    float sum12 = 0.f;
#pragma unroll
    for (int k = 0; k < NBASE; k++) { s[k] = __expf(s[k] - m12); sum12 += s[k]; }

    float m8 = s[NBASE];
#pragma unroll
    for (int k = NBASE + 1; k < KCLS; k++) m8 = fmaxf(m8, s[k]);
    float sum8 = 0.f;
#pragma unroll
    for (int k = NBASE; k < KCLS; k++) { s[k] = __expf(s[k] - m8); sum8 += s[k]; }

    float sig = 1.f / (1.f + __expf(-bv));
    // analytic: renormalization denominator == 1
    float cb = sig / sum12;
    float cn = (1.f - sig) / sum8;
#pragma unroll
    for (int k = 0; k < NBASE; k++) s[k] *= cb;
#pragma unroll
    for (int k = NBASE; k < KCLS; k++) s[k] *= cn;

    float4* o = reinterpret_cast<float4*>(out + (size_t)i * KCLS);
    o[0] = make_float4(s[0], s[1], s[2], s[3]);
    o[1] = make_float4(s[4], s[5], s[6], s[7]);
    o[2] = make_float4(s[8], s[9], s[10], s[11]);
    o[3] = make_float4(s[12], s[13], s[14], s[15]);
    o[4] = make_float4(s[16], s[17], s[18], s[19]);
  }
}

// group: counting-sort memberships into per-proposal buckets. 256 thr, 2048/blk.
__device__ __forceinline__ void dev_group(int gb,
    const int* __restrict__ pidx, const int* __restrict__ pid,
    int* __restrict__ cnt, int* __restrict__ bucket, int m) {
  __shared__ int hist[PPROP];
  __shared__ int bs[PPROP];
  int t = threadIdx.x;
  for (int j = t; j < PPROP; j += 256) hist[j] = 0;
  __syncthreads();

  int base = gb * 2048;
  int p[8], q[8], lr[8];
#pragma unroll
  for (int j = 0; j < 8; j++) {
    int i = base + j * 256 + t;
    if (i < m) {
      p[j] = pid[i];
      q[j] = pidx[i];
      lr[j] = lds_addi(&hist[p[j]], 1);
    } else {
      p[j] = -1; q[j] = 0; lr[j] = 0;
    }
  }
  __syncthreads();
  for (int j = t; j < PPROP; j += 256) {
    int h = hist[j];
    bs[j] = h ? glb_addi(&cnt[j], h) : 0;
  }
  __syncthreads();
#pragma unroll
  for (int j = 0; j < 8; j++) {
    if (p[j] >= 0) {
      int pos = bs[p[j]] + lr[j];
      if (pos < SLOTS) bucket[(size_t)p[j] * SLOTS + pos] = q[j];
    }
  }
}

// psum: per-proposal mean via register accumulation, 256 threads, block = proposal.
__device__ __forceinline__ void dev_psum(int p,
    const int4* __restrict__ packed, const int* __restrict__ cnt,
    const int* __restrict__ bucket, float* __restrict__ psem,
    float* __restrict__ pbin) {
  __shared__ float wacc[4 * 19];
  int t = threadIdx.x;
  int c = cnt[p];
  int cc = c < SLOTS ? c : SLOTS;

  float s[19];
#pragma unroll
  for (int k = 0; k < 19; k++) s[k] = 0.f;

  const int* bk = bucket + (size_t)p * SLOTS;
  for (int j = t; j < cc; j += 256) {
    int q = bk[j];
    const int4* r = packed + (size_t)q * 3;
    int4 a = r[0], b = r[1], cw = r[2];
    s[0] += bflo(a.x);  s[1] += bfhi(a.x);
    s[2] += bflo(a.y);  s[3] += bfhi(a.y);
    s[4] += bflo(a.z);  s[5] += bfhi(a.z);
    s[6] += bflo(a.w);  s[7] += bfhi(a.w);
    s[8] += bflo(b.x);  s[9] += bfhi(b.x);
    s[10] += bflo(b.y); s[11] += bfhi(b.y);
    s[12] += bflo(b.z); s[13] += bfhi(b.z);
    s[14] += bflo(b.w); s[15] += bfhi(b.w);
    s[16] += bflo(cw.x); s[17] += bfhi(cw.x);
    s[18] += bflo(cw.y);
  }

  int lane = t & 63, w = t >> 6;
#pragma unroll
  for (int k = 0; k < 19; k++) s[k] = red64(s[k]);
  if (lane == 63) {
#pragma unroll
    for (int k = 0; k < 19; k++) wacc[w * 19 + k] = s[k];
  }
  __syncthreads();
  if (t < 19) {
    float v = wacc[t] + wacc[19 + t] + wacc[38 + t] + wacc[57 + t];
    float inv = 1.f / fmaxf((float)c, 1.f);
    if (t < 18) psem[p * 18 + t] = v * inv;
    else pbin[p] = v * inv;
  }
}

// heads: MFMA mask/iou + BN stats. wave-indexed over 16-point tiles.
__device__ __forceinline__ void dev_heads(int wave, int nwaves,
    const float* __restrict__ feats, const float* __restrict__ W1,
    const float* __restrict__ Wm1, const float* __restrict__ bm1,
    const float* __restrict__ Wm2, const float* __restrict__ bm2,
    const float* __restrict__ Wi,  const float* __restrict__ bi,
    float* __restrict__ mask_out, float* __restrict__ iou_out,
    float* __restrict__ stats, int n) {
  __shared__ float red[64];
  int t = threadIdx.x;
  int lane = t & 63;
  int nn = lane & 15;
  int grp = lane >> 4;

  bf16x8 bWm0 = make_bfrag(Wm1, lane, 0);
  bf16x8 bWm1f = make_bfrag(Wm1, lane, 16);
  bf16x8 bW10 = make_bfrag(W1, lane, 0);
  bf16x8 bW11 = make_bfrag(W1, lane, 16);
  bf16x8 bWi;
  {
    int kb = grp * 8;
#pragma unroll
    for (int e = 0; e < 8; e++) bWi[e] = (nn == 0) ? f2bf(Wi[kb + e]) : (short)0;
  }
  float bm1a = bm1[nn], bm1b = bm1[nn + 16];
  float wm2a = Wm2[nn], wm2b = Wm2[nn + 16];
  float bm2v = bm2[0], biv = bi[0];

  float hs0 = 0.f, hs1 = 0.f, hq0 = 0.f, hq1 = 0.f;
  int ntiles = (n + 15) >> 4;

  for (int tile = wave; tile < ntiles; tile += nwaves) {
    int p0 = tile << 4;
    int row = p0 + nn;
    bool rv = row < n;
    const float4* fr = reinterpret_cast<const float4*>(
        feats + (size_t)(rv ? row : (n - 1)) * CDIM + grp * 8);
    float4 v0 = fr[0], v1 = fr[1];
    bf16x8 a;
    if (rv) {
      a[0] = f2bf(v0.x); a[1] = f2bf(v0.y); a[2] = f2bf(v0.z); a[3] = f2bf(v0.w);
      a[4] = f2bf(v1.x); a[5] = f2bf(v1.y); a[6] = f2bf(v1.z); a[7] = f2bf(v1.w);
    } else {
#pragma unroll
      for (int e = 0; e < 8; e++) a[e] = 0;
    }

    f32x4 am0, am1, ah0, ah1, ai;
#pragma unroll
    for (int r = 0; r < 4; r++) { am0[r] = bm1a; am1[r] = bm1b; ah0[r] = 0.f; ah1[r] = 0.f; ai[r] = 0.f; }

    am0 = __builtin_amdgcn_mfma_f32_16x16x32_bf16(a, bWm0,  am0, 0, 0, 0);
    am1 = __builtin_amdgcn_mfma_f32_16x16x32_bf16(a, bWm1f, am1, 0, 0, 0);
    ah0 = __builtin_amdgcn_mfma_f32_16x16x32_bf16(a, bW10,  ah0, 0, 0, 0);
    ah1 = __builtin_amdgcn_mfma_f32_16x16x32_bf16(a, bW11,  ah1, 0, 0, 0);
    ai  = __builtin_amdgcn_mfma_f32_16x16x32_bf16(a, bWi,   ai,  0, 0, 0);

    float t0 = fmaxf(am0[0], 0.f) * wm2a + fmaxf(am1[0], 0.f) * wm2b;
    float t1 = fmaxf(am0[1], 0.f) * wm2a + fmaxf(am1[1], 0.f) * wm2b;
    float t2 = fmaxf(am0[2], 0.f) * wm2a + fmaxf(am1[2], 0.f) * wm2b;
    float t3 = fmaxf(am0[3], 0.f) * wm2a + fmaxf(am1[3], 0.f) * wm2b;
    t0 = red16(t0); t1 = red16(t1); t2 = red16(t2); t3 = red16(t3);

    if (p0 + 16 <= n) {
      if (nn == 15) {
        *reinterpret_cast<float4*>(mask_out + p0 + grp * 4) =
            make_float4(t0 + bm2v, t1 + bm2v, t2 + bm2v, t3 + bm2v);
      }
      if (nn == 0) {
        *reinterpret_cast<float4*>(iou_out + p0 + grp * 4) =
            make_float4(ai[0] + biv, ai[1] + biv, ai[2] + biv, ai[3] + biv);
      }
    } else {
      if (nn == 15) {
        float tv[4] = {t0, t1, t2, t3};
#pragma unroll
        for (int r = 0; r < 4; r++) {
          int p = p0 + grp * 4 + r;
          if (p < n) mask_out[p] = tv[r] + bm2v;
        }
      }
      if (nn == 0) {
#pragma unroll
        for (int r = 0; r < 4; r++) {
          int p = p0 + grp * 4 + r;
          if (p < n) iou_out[p] = ai[r] + biv;
        }
      }
    }

#pragma unroll
    for (int r = 0; r < 4; r++) {
      hs0 += ah0[r]; hq0 = fmaf(ah0[r], ah0[r], hq0);
      hs1 += ah1[r]; hq1 = fmaf(ah1[r], ah1[r], hq1);
    }
  }

  __syncthreads();
  for (int q = t; q < 64; q += 256) red[q] = 0.f;
  __syncthreads();
  lds_addf(&red[nn], hs0);       lds_addf(&red[nn + 16], hs1);
  lds_addf(&red[32 + nn], hq0);  lds_addf(&red[48 + nn], hq1);
  __syncthreads();
  for (int q = t; q < 64; q += 256) glb_addf(&stats[q], red[q]);
}

// ================= kernels =================

__global__ void k_zero(float* __restrict__ head, int nfloats, int* __restrict__ cnt) {
  int t = blockIdx.x * blockDim.x + threadIdx.x;
  int stride = gridDim.x * blockDim.x;
  for (int i = t; i < nfloats; i += stride) head[i] = 0.f;
  for (int i = t; i < PPROP; i += stride) cnt[i] = 0;
}

// phase 1: scores-blocks [0,sb) || group-blocks [sb, sb+nb)  (independent work;
// round-11 lesson: same-stream kernels serialize, block-partition merges overlap
// group's atomic/idx latency under scores' streaming BW)
__global__ __launch_bounds__(256, 4) void k_p1(
    const float* __restrict__ sem, const float* __restrict__ bin,
    float* __restrict__ out, int4* __restrict__ packed, int n,
    const int* __restrict__ pidx, const int* __restrict__ pid,
    int* __restrict__ cnt, int* __restrict__ bucket, int m, int sb) {
  if ((int)blockIdx.x < sb) {
    dev_scores(blockIdx.x, sb, sem, bin, out, packed, n);
  } else {
    dev_group(blockIdx.x - sb, pidx, pid, cnt, bucket, m);
  }
}

// phase 2: psum-blocks [0,PPROP) || heads-blocks [PPROP, PPROP+hb)
// (psum's random-gather latency hides under heads' MFMA+BW stream)
__global__ __launch_bounds__(256, 4) void k_p2(
    const int4* __restrict__ packed, const int* __restrict__ cnt,
    const int* __restrict__ bucket, float* __restrict__ psem,
    float* __restrict__ pbin,
    const float* __restrict__ feats, const float* __restrict__ W1,
    const float* __restrict__ Wm1, const float* __restrict__ bm1,
    const float* __restrict__ Wm2, const float* __restrict__ bm2,
    const float* __restrict__ Wi,  const float* __restrict__ bi,
    float* __restrict__ mask_out, float* __restrict__ iou_out,
    float* __restrict__ stats, int n, int hb) {
  if ((int)blockIdx.x < PPROP) {
    dev_psum(blockIdx.x, packed, cnt, bucket, psem, pbin);
  } else {
    int b = blockIdx.x - PPROP;
    int wave = (b * 256 + threadIdx.x) >> 6;
    dev_heads(wave, hb * 4, feats, W1, Wm1, bm1, Wm2, bm2, Wi, bi,
              mask_out, iou_out, stats, n);
  }
}

// ---- fallback standalone kernels (ws too small for grouped path) ----
__global__ void k_scores_s(const float* __restrict__ sem, const float* __restrict__ bin,
                           float* __restrict__ out, int4* __restrict__ packed, int n) {
  dev_scores(blockIdx.x, gridDim.x, sem, bin, out, packed, n);
}

__global__ __launch_bounds__(256, 4) void k_heads_s(const float* __restrict__ feats,
    const float* __restrict__ W1,
    const float* __restrict__ Wm1, const float* __restrict__ bm1,
    const float* __restrict__ Wm2, const float* __restrict__ bm2,
    const float* __restrict__ Wi,  const float* __restrict__ bi,
    float* __restrict__ mask_out, float* __restrict__ iou_out,
    float* __restrict__ stats, int n) {
  int wave = (blockIdx.x * 256 + threadIdx.x) >> 6;
  dev_heads(wave, gridDim.x * 4, feats, W1, Wm1, bm1, Wm2, bm2, Wi, bi,
            mask_out, iou_out, stats, n);
}

__global__ __launch_bounds__(512) void k_scatter_p(const int4* __restrict__ packed,
    const int* __restrict__ pidx, const int* __restrict__ pid,
    float* __restrict__ acc, int m) {
  __shared__ float tbl[PPROP * TBLW];
  for (int t = threadIdx.x; t < PPROP * TBLW; t += blockDim.x) tbl[t] = 0.f;
  __syncthreads();
  int stride = gridDim.x * blockDim.x;
  for (int i = blockIdx.x * blockDim.x + threadIdx.x; i < m; i += stride) {
    int q = pidx[i];
    int p = pid[i];
    const int4* r = packed + (size_t)q * 3;
    int4 a = r[0], b = r[1], c = r[2];
    float* t = tbl + p * TBLW;
    lds_addf(t + 0, bflo(a.x)); lds_addf(t + 1, bfhi(a.x));
    lds_addf(t + 2, bflo(a.y)); lds_addf(t + 3, bfhi(a.y));
    lds_addf(t + 4, bflo(a.z)); lds_addf(t + 5, bfhi(a.z));
    lds_addf(t + 6, bflo(a.w)); lds_addf(t + 7, bfhi(a.w));
    lds_addf(t + 8, bflo(b.x)); lds_addf(t + 9, bfhi(b.x));
    lds_addf(t +10, bflo(b.y)); lds_addf(t +11, bfhi(b.y));
    lds_addf(t +12, bflo(b.z)); lds_addf(t +13, bfhi(b.z));
    lds_addf(t +14, bflo(b.w)); lds_addf(t +15, bfhi(b.w));
    lds_addf(t +16, bflo(c.x)); lds_addf(t +17, bfhi(c.x));
    lds_addf(t +18, bflo(c.y));
    lds_addf(t +19, 1.f);
  }
  __syncthreads();
  for (int t = threadIdx.x; t < PPROP * TBLW; t += blockDim.x) {
    float v = tbl[t];
    if (v != 0.f) glb_addf(acc + t, v);
  }
}

__global__ __launch_bounds__(512) void k_scatter(const float* __restrict__ sem,
    const float* __restrict__ bin, const int* __restrict__ pidx,
    const int* __restrict__ pid, float* __restrict__ acc, int m) {
  __shared__ float tbl[PPROP * TBLW];
  for (int t = threadIdx.x; t < PPROP * TBLW; t += blockDim.x) tbl[t] = 0.f;
  __syncthreads();
  int stride = gridDim.x * blockDim.x;
  for (int i = blockIdx.x * blockDim.x + threadIdx.x; i < m; i += stride) {
    int q = pidx[i];
    int p = pid[i];
    const float* row = sem + (size_t)q * KCLS;
    float2 a  = *reinterpret_cast<const float2*>(row + 2);
    float4 c0 = *reinterpret_cast<const float4*>(row + 4);
    float4 c1 = *reinterpret_cast<const float4*>(row + 8);
    float4 c2 = *reinterpret_cast<const float4*>(row + 12);
    float4 c3 = *reinterpret_cast<const float4*>(row + 16);
    float bv = bin[q];
    float* t = tbl + p * TBLW;
    lds_addf(t + 0, a.x);  lds_addf(t + 1, a.y);
    lds_addf(t + 2, c0.x); lds_addf(t + 3, c0.y); lds_addf(t + 4, c0.z); lds_addf(t + 5, c0.w);
    lds_addf(t + 6, c1.x); lds_addf(t + 7, c1.y); lds_addf(t + 8, c1.z); lds_addf(t + 9, c1.w);
    lds_addf(t +10, c2.x); lds_addf(t +11, c2.y); lds_addf(t +12, c2.z); lds_addf(t +13, c2.w);
    lds_addf(t +14, c3.x); lds_addf(t +15, c3.y); lds_addf(t +16, c3.z); lds_addf(t +17, c3.w);
    lds_addf(t +18, bv);
    lds_addf(t +19, 1.f);
  }
  __syncthreads();
  for (int t = threadIdx.x; t < PPROP * TBLW; t += blockDim.x) {
    float v = tbl[t];
    if (v != 0.f) glb_addf(acc + t, v);
  }
}

__global__ void k_finalize(const float* __restrict__ acc,
                           float* __restrict__ psem, float* __restrict__ pbin) {
  int p = blockIdx.x * blockDim.x + threadIdx.x;
  if (p < PPROP) {
    const float* t = acc + p * TBLW;
    float cnt = fmaxf(t[19], 1.f);
    float r = 1.f / cnt;
#pragma unroll
    for (int c = 0; c < 18; c++) psem[p * 18 + c] = t[c] * r;
    pbin[p] = t[18] * r;
  }
}

// ---------------- pt_offsets via MFMA, BN prep inlined ----------------
// stats hold S=sum(f@W1), Q=sum((f@W1)^2); var shift-invariant so b1 cancels;
// tc = be1 - mean*sc makes (h_noBias*sc + tc) == BN(h_full).
__global__ __launch_bounds__(256, 4) void k_offsets_m(const float* __restrict__ feats,
    const float* __restrict__ W1,
    const float* __restrict__ W2, const float* __restrict__ b2,
    const float* __restrict__ stats, const float* __restrict__ g1,
    const float* __restrict__ be1, float* __restrict__ out_off, int n, float invN) {
  int t = threadIdx.x;
  int lane = t & 63;
  int nn = lane & 15;
  int grp = lane >> 4;

  bf16x8 bW10 = make_bfrag(W1, lane, 0);
  bf16x8 bW11 = make_bfrag(W1, lane, 16);
  float scA, tcA, scB, tcB;
  {
    float meanA = stats[nn] * invN;
    float varA  = stats[CDIM + nn] * invN - meanA * meanA;
    scA = g1[nn] * rsqrtf(varA + 1e-4f);
    tcA = be1[nn] - meanA * scA;
    float meanB = stats[nn + 16] * invN;
    float varB  = stats[CDIM + nn + 16] * invN - meanB * meanB;
    scB = g1[nn + 16] * rsqrtf(varB + 1e-4f);
    tcB = be1[nn + 16] - meanB * scB;
  }
  float wxA = W2[nn * 3 + 0], wxB = W2[(nn + 16) * 3 + 0];
  float wyA = W2[nn * 3 + 1], wyB = W2[(nn + 16) * 3 + 1];
  float wzA = W2[nn * 3 + 2], wzB = W2[(nn + 16) * 3 + 2];
  float b2x = b2[0], b2y = b2[1], b2z = b2[2];

  int wave   = (blockIdx.x * blockDim.x + t) >> 6;
  int nwaves = (gridDim.x * blockDim.x) >> 6;
  int ntiles = (n + 15) >> 4;

  for (int tile = wave; tile < ntiles; tile += nwaves) {
    int p0 = tile << 4;
    int row = p0 + nn;
    bool rv = row < n;
    const float4* fr = reinterpret_cast<const float4*>(
        feats + (size_t)(rv ? row : (n - 1)) * CDIM + grp * 8);
    float4 v0 = fr[0], v1 = fr[1];
    bf16x8 a;
    if (rv) {
      a[0] = f2bf(v0.x); a[1] = f2bf(v0.y); a[2] = f2bf(v0.z); a[3] = f2bf(v0.w);
      a[4] = f2bf(v1.x); a[5] = f2bf(v1.y); a[6] = f2bf(v1.z); a[7] = f2bf(v1.w);
    } else {
#pragma unroll
      for (int e = 0; e < 8; e++) a[e] = 0;
    }

    f32x4 ah0 = {0.f, 0.f, 0.f, 0.f}, ah1 = {0.f, 0.f, 0.f, 0.f};
    ah0 = __builtin_amdgcn_mfma_f32_16x16x32_bf16(a, bW10, ah0, 0, 0, 0);
    ah1 = __builtin_amdgcn_mfma_f32_16x16x32_bf16(a, bW11, ah1, 0, 0, 0);

    float tx[4], ty[4], tz[4];
#pragma unroll
    for (int r = 0; r < 4; r++) {
      float y0 = fmaxf(fmaf(ah0[r], scA, tcA), 0.f);
      float y1 = fmaxf(fmaf(ah1[r], scB, tcB), 0.f);
      tx[r] = red16(y0 * wxA + y1 * wxB);
      ty[r] = red16(y0 * wyA + y1 * wyB);
      tz[r] = red16(y0 * wzA + y1 * wzB);
    }

    if (nn == 15) {
      int pbase = p0 + grp * 4;
      if (pbase + 4 <= n) {
        float4* o = reinterpret_cast<float4*>(out_off + (size_t)pbase * 3);
        o[0] = make_float4(tx[0] + b2x, ty[0] + b2y, tz[0] + b2z, tx[1] + b2x);
        o[1] = make_float4(ty[1] + b2y, tz[1] + b2z, tx[2] + b2x, ty[2] + b2y);
        o[2] = make_float4(tz[2] + b2z, tx[3] + b2x, ty[3] + b2y, tz[3] + b2z);
      } else {
#pragma unroll
        for (int r = 0; r < 4; r++) {
          int p = pbase + r;
          if (p < n) {
            out_off[(size_t)p * 3 + 0] = tx[r] + b2x;
            out_off[(size_t)p * 3 + 1] = ty[r] + b2y;
            out_off[(size_t)p * 3 + 2] = tz[r] + b2z;
          }
        }
      }
    }
  }
}

extern "C" void kernel_launch(void* const* d_in, const int* in_sizes, int n_in,
                              void* d_out, int out_size, void* d_ws, size_t ws_size,
                              hipStream_t stream) {
  const float* feats = (const float*)d_in[0];
  const float* sem   = (const float*)d_in[1];
  const float* bin   = (const float*)d_in[2];
  const int*   pidx  = (const int*)d_in[3];
  const int*   pid   = (const int*)d_in[4];
  const float* W1  = (const float*)d_in[5];
  // b1 (d_in[6]) cancels analytically: BN var is shift-invariant, mean shift folds
  const float* g1  = (const float*)d_in[7];
  const float* be1 = (const float*)d_in[8];
  const float* W2  = (const float*)d_in[9];
  const float* b2  = (const float*)d_in[10];
  const float* Wm1 = (const float*)d_in[11];
  const float* bm1 = (const float*)d_in[12];
  const float* Wm2 = (const float*)d_in[13];
  const float* bm2 = (const float*)d_in[14];
  const float* Wi  = (const float*)d_in[15];
  const float* bi  = (const float*)d_in[16];

  int n = in_sizes[2];   // binary_scores is (N,1)
  int m = in_sizes[3];   // memberships

  float* out = (float*)d_out;
  float* o_scores = out;
  float* o_off  = out + (size_t)n * KCLS;
  float* o_psem = o_off + (size_t)n * 3;
  float* o_pbin = o_psem + (size_t)PPROP * 18;
  float* o_mask = o_pbin + PPROP;
  float* o_iou  = o_mask + n;

  char* wsb = (char*)d_ws;
  float* stats = (float*)wsb;               // 64 floats: S[32], Q[32]
  float* acc   = stats + 2 * CDIM;          // P*TBLW floats (fallback paths)
  size_t head_floats = 2 * CDIM + PPROP * TBLW;
  int* cnt = (int*)(wsb + head_floats * sizeof(float));   // 1024 ints
  size_t pk_off = (head_floats * sizeof(float) + PPROP * sizeof(int) + 15) & ~(size_t)15;
  size_t pk_bytes = (size_t)n * PKW * sizeof(short);      // 16B multiple
  size_t bk_off = pk_off + pk_bytes;
  size_t bk_bytes = (size_t)PPROP * SLOTS * sizeof(int);
  bool use_packed  = (pk_off + pk_bytes) <= ws_size;
  bool use_grouped = use_packed && (bk_off + bk_bytes) <= ws_size;
  int4* packed = use_packed ? (int4*)(wsb + pk_off) : nullptr;
  int* bucket  = (int*)(wsb + bk_off);

  if (use_grouped) {
    // zero just stats + cnt (acc unused on this path)
    k_zero<<<2, 256, 0, stream>>>(stats, 2 * CDIM, cnt);
    int sb = 2048;
    int nb = (m + 2047) / 2048;
    k_p1<<<sb + nb, 256, 0, stream>>>(sem, bin, o_scores, packed, n,
                                      pidx, pid, cnt, bucket, m, sb);
    int hb = 2048;
    k_p2<<<PPROP + hb, 256, 0, stream>>>(packed, cnt, bucket, o_psem, o_pbin,
                                         feats, W1, Wm1, bm1, Wm2, bm2, Wi, bi,
                                         o_mask, o_iou, stats, n, hb);
  } else {
    k_zero<<<32, 256, 0, stream>>>(stats, (int)head_floats, cnt);
    k_scores_s<<<2048, 256, 0, stream>>>(sem, bin, o_scores, packed, n);
    if (use_packed) {
      k_scatter_p<<<512, 512, 0, stream>>>(packed, pidx, pid, acc, m);
    } else {
      k_scatter <<<512, 512, 0, stream>>>(sem, bin, pidx, pid, acc, m);
    }
    k_finalize<<<4, 256, 0, stream>>>(acc, o_psem, o_pbin);
    k_heads_s<<<2048, 256, 0, stream>>>(feats, W1, Wm1, bm1, Wm2, bm2, Wi, bi,
                                        o_mask, o_iou, stats, n);
  }
  k_offsets_m<<<2048, 256, 0, stream>>>(feats, W1, W2, b2, stats, g1, be1,
                                        o_off, n, 1.0f / (float)n);
}

// Round 13
// 305.655 us; speedup vs baseline: 1.1193x; 1.0447x over previous
//
#include <hip/hip_runtime.h>
#include <hip/hip_bf16.h>

#define CDIM 32
#define KCLS 20
#define NBASE 12
#define PPROP 1024
#define TBLW 20   // 18 sem cols (2..19) + binary + count (fallback path)
#define PKW 24    // packed row: 24 shorts = 48B (18 sem bf16, bin bf16, 5 pad)
#define SLOTS 3072  // per-proposal bucket capacity (mean 1953, +25 sigma)

typedef __attribute__((ext_vector_type(8))) short bf16x8;
typedef __attribute__((ext_vector_type(4))) float f32x4;

__device__ __forceinline__ void lds_addf(float* p, float v) {
  __hip_atomic_fetch_add(p, v, __ATOMIC_RELAXED, __HIP_MEMORY_SCOPE_WORKGROUP);
}
__device__ __forceinline__ int lds_addi(int* p, int v) {
  return __hip_atomic_fetch_add(p, v, __ATOMIC_RELAXED, __HIP_MEMORY_SCOPE_WORKGROUP);
}
__device__ __forceinline__ void glb_addf(float* p, float v) {
  __hip_atomic_fetch_add(p, v, __ATOMIC_RELAXED, __HIP_MEMORY_SCOPE_AGENT);
}
__device__ __forceinline__ int glb_addi(int* p, int v) {
  return __hip_atomic_fetch_add(p, v, __ATOMIC_RELAXED, __HIP_MEMORY_SCOPE_AGENT);
}

__device__ __forceinline__ short f2bf(float x) {
  unsigned u = __builtin_bit_cast(unsigned, x);
  unsigned r = (u + 0x7fffu + ((u >> 16) & 1u)) >> 16;
  return (short)r;
}
__device__ __forceinline__ unsigned pk2(float lo, float hi) {
  return (unsigned)(unsigned short)f2bf(lo) | ((unsigned)(unsigned short)f2bf(hi) << 16);
}
__device__ __forceinline__ float bflo(unsigned u) {
  return __builtin_bit_cast(float, u << 16);
}
__device__ __forceinline__ float bfhi(unsigned u) {
  return __builtin_bit_cast(float, u & 0xffff0000u);
}

template <int CTRL>
__device__ __forceinline__ float dpp_add(float x) {
  int s = __builtin_amdgcn_update_dpp(0, __builtin_bit_cast(int, x),
                                      CTRL, 0xf, 0xf, true);
  return x + __builtin_bit_cast(float, s);
}
__device__ __forceinline__ float red16(float x) {
  x = dpp_add<0x111>(x);
  x = dpp_add<0x112>(x);
  x = dpp_add<0x114>(x);
  x = dpp_add<0x118>(x);
  return x;
}
__device__ __forceinline__ float red64(float x) {
  x = red16(x);
  x = dpp_add<0x142>(x);
  x = dpp_add<0x143>(x);
  return x;
}

__device__ __forceinline__ bf16x8 make_bfrag(const float* __restrict__ W,
                                             int lane, int colOff) {
  int n = (lane & 15) + colOff;
  int kb = (lane >> 4) * 8;
  bf16x8 b;
#pragma unroll
  for (int e = 0; e < 8; e++) b[e] = f2bf(W[(kb + e) * CDIM + n]);
  return b;
}

// ================= device bodies =================

__device__ __forceinline__ void dev_scores(int vb, int vgrid,
    const float* __restrict__ sem, const float* __restrict__ bin,
    float* __restrict__ out, int4* __restrict__ packed, int n) {
  int stride = vgrid * 256;
  for (int i = vb * 256 + threadIdx.x; i < n; i += stride) {
    const float4* r = reinterpret_cast<const float4*>(sem + (size_t)i * KCLS);
    float s[KCLS];
    float4 v;
    v = r[0]; s[0]=v.x; s[1]=v.y; s[2]=v.z; s[3]=v.w;
    v = r[1]; s[4]=v.x; s[5]=v.y; s[6]=v.z; s[7]=v.w;
    v = r[2]; s[8]=v.x; s[9]=v.y; s[10]=v.z; s[11]=v.w;
    v = r[3]; s[12]=v.x; s[13]=v.y; s[14]=v.z; s[15]=v.w;
    v = r[4]; s[16]=v.x; s[17]=v.y; s[18]=v.z; s[19]=v.w;
    float bv = bin[i];

    if (packed) {
      int4 p0, p1, p2;
      p0.x = pk2(s[2],  s[3]);  p0.y = pk2(s[4],  s[5]);
      p0.z = pk2(s[6],  s[7]);  p0.w = pk2(s[8],  s[9]);
      p1.x = pk2(s[10], s[11]); p1.y = pk2(s[12], s[13]);
      p1.z = pk2(s[14], s[15]); p1.w = pk2(s[16], s[17]);
      p2.x = pk2(s[18], s[19]); p2.y = pk2(bv, 0.f);
      p2.z = 0; p2.w = 0;
      int4* pr = packed + (size_t)i * 3;
      pr[0] = p0; pr[1] = p1; pr[2] = p2;
    }

    float m12 = s[0];
#pragma unroll
    for (int k = 1; k < NBASE; k++) m12 = fmaxf(m12, s[k]);
    float sum12 = 0.f;
#pragma unroll
    for (int k = 0; k < NBASE; k++) { s[k] = __expf(s[k] - m12); sum12 += s[k]; }

    float m8 = s[NBASE];
#pragma unroll
    for (int k = NBASE + 1; k < KCLS; k++) m8 = fmaxf(m8, s[k]);
    float sum8 = 0.f;
#pragma unroll
    for (int k = NBASE; k < KCLS; k++) { s[k] = __expf(s[k] - m8); sum8 += s[k]; }

    float sig = 1.f / (1.f + __expf(-bv));
    // analytic: renormalization denominator == 1
    float cb = sig / sum12;
    float cn = (1.f - sig) / sum8;
#pragma unroll
    for (int k = 0; k < NBASE; k++) s[k] *= cb;
#pragma unroll
    for (int k = NBASE; k < KCLS; k++) s[k] *= cn;

    float4* o = reinterpret_cast<float4*>(out + (size_t)i * KCLS);
    o[0] = make_float4(s[0], s[1], s[2], s[3]);
    o[1] = make_float4(s[4], s[5], s[6], s[7]);
    o[2] = make_float4(s[8], s[9], s[10], s[11]);
    o[3] = make_float4(s[12], s[13], s[14], s[15]);
    o[4] = make_float4(s[16], s[17], s[18], s[19]);
  }
}

__device__ __forceinline__ void dev_group(int gb,
    const int* __restrict__ pidx, const int* __restrict__ pid,
    int* __restrict__ cnt, int* __restrict__ bucket, int m) {
  __shared__ int hist[PPROP];
  __shared__ int bs[PPROP];
  int t = threadIdx.x;
  for (int j = t; j < PPROP; j += 256) hist[j] = 0;
  __syncthreads();

  int base = gb * 2048;
  int p[8], q[8], lr[8];
#pragma unroll
  for (int j = 0; j < 8; j++) {
    int i = base + j * 256 + t;
    if (i < m) {
      p[j] = pid[i];
      q[j] = pidx[i];
      lr[j] = lds_addi(&hist[p[j]], 1);
    } else {
      p[j] = -1; q[j] = 0; lr[j] = 0;
    }
  }
  __syncthreads();
  for (int j = t; j < PPROP; j += 256) {
    int h = hist[j];
    bs[j] = h ? glb_addi(&cnt[j], h) : 0;
  }
  __syncthreads();
#pragma unroll
  for (int j = 0; j < 8; j++) {
    if (p[j] >= 0) {
      int pos = bs[p[j]] + lr[j];
      if (pos < SLOTS) bucket[(size_t)p[j] * SLOTS + pos] = q[j];
    }
  }
}

__device__ __forceinline__ void dev_psum(int p,
    const int4* __restrict__ packed, const int* __restrict__ cnt,
    const int* __restrict__ bucket, float* __restrict__ psem,
    float* __restrict__ pbin) {
  __shared__ float wacc[4 * 19];
  int t = threadIdx.x;
  int c = cnt[p];
  int cc = c < SLOTS ? c : SLOTS;

  float s[19];
#pragma unroll
  for (int k = 0; k < 19; k++) s[k] = 0.f;

  const int* bk = bucket + (size_t)p * SLOTS;
  for (int j = t; j < cc; j += 256) {
    int q = bk[j];
    const int4* r = packed + (size_t)q * 3;
    int4 a = r[0], b = r[1], cw = r[2];
    s[0] += bflo(a.x);  s[1] += bfhi(a.x);
    s[2] += bflo(a.y);  s[3] += bfhi(a.y);
    s[4] += bflo(a.z);  s[5] += bfhi(a.z);
    s[6] += bflo(a.w);  s[7] += bfhi(a.w);
    s[8] += bflo(b.x);  s[9] += bfhi(b.x);
    s[10] += bflo(b.y); s[11] += bfhi(b.y);
    s[12] += bflo(b.z); s[13] += bfhi(b.z);
    s[14] += bflo(b.w); s[15] += bfhi(b.w);
    s[16] += bflo(cw.x); s[17] += bfhi(cw.x);
    s[18] += bflo(cw.y);
  }

  int lane = t & 63, w = t >> 6;
#pragma unroll
  for (int k = 0; k < 19; k++) s[k] = red64(s[k]);
  if (lane == 63) {
#pragma unroll
    for (int k = 0; k < 19; k++) wacc[w * 19 + k] = s[k];
  }
  __syncthreads();
  if (t < 19) {
    float v = wacc[t] + wacc[19 + t] + wacc[38 + t] + wacc[57 + t];
    float inv = 1.f / fmaxf((float)c, 1.f);
    if (t < 18) psem[p * 18 + t] = v * inv;
    else pbin[p] = v * inv;
  }
}

__device__ __forceinline__ void dev_heads(int wave, int nwaves,
    const float* __restrict__ feats, const float* __restrict__ W1,
    const float* __restrict__ Wm1, const float* __restrict__ bm1,
    const float* __restrict__ Wm2, const float* __restrict__ bm2,
    const float* __restrict__ Wi,  const float* __restrict__ bi,
    float* __restrict__ mask_out, float* __restrict__ iou_out,
    float* __restrict__ stats, int n) {
  __shared__ float red[64];
  int t = threadIdx.x;
  int lane = t & 63;
  int nn = lane & 15;
  int grp = lane >> 4;

  bf16x8 bWm0 = make_bfrag(Wm1, lane, 0);
  bf16x8 bWm1f = make_bfrag(Wm1, lane, 16);
  bf16x8 bW10 = make_bfrag(W1, lane, 0);
  bf16x8 bW11 = make_bfrag(W1, lane, 16);
  bf16x8 bWi;
  {
    int kb = grp * 8;
#pragma unroll
    for (int e = 0; e < 8; e++) bWi[e] = (nn == 0) ? f2bf(Wi[kb + e]) : (short)0;
  }
  float bm1a = bm1[nn], bm1b = bm1[nn + 16];
  float wm2a = Wm2[nn], wm2b = Wm2[nn + 16];
  float bm2v = bm2[0], biv = bi[0];

  float hs0 = 0.f, hs1 = 0.f, hq0 = 0.f, hq1 = 0.f;
  int ntiles = (n + 15) >> 4;

  for (int tile = wave; tile < ntiles; tile += nwaves) {
    int p0 = tile << 4;
    int row = p0 + nn;
    bool rv = row < n;
    const float4* fr = reinterpret_cast<const float4*>(
        feats + (size_t)(rv ? row : (n - 1)) * CDIM + grp * 8);
    float4 v0 = fr[0], v1 = fr[1];
    bf16x8 a;
    if (rv) {
      a[0] = f2bf(v0.x); a[1] = f2bf(v0.y); a[2] = f2bf(v0.z); a[3] = f2bf(v0.w);
      a[4] = f2bf(v1.x); a[5] = f2bf(v1.y); a[6] = f2bf(v1.z); a[7] = f2bf(v1.w);
    } else {
#pragma unroll
      for (int e = 0; e < 8; e++) a[e] = 0;
    }

    f32x4 am0, am1, ah0, ah1, ai;
#pragma unroll
    for (int r = 0; r < 4; r++) { am0[r] = bm1a; am1[r] = bm1b; ah0[r] = 0.f; ah1[r] = 0.f; ai[r] = 0.f; }

    am0 = __builtin_amdgcn_mfma_f32_16x16x32_bf16(a, bWm0,  am0, 0, 0, 0);
    am1 = __builtin_amdgcn_mfma_f32_16x16x32_bf16(a, bWm1f, am1, 0, 0, 0);
    ah0 = __builtin_amdgcn_mfma_f32_16x16x32_bf16(a, bW10,  ah0, 0, 0, 0);
    ah1 = __builtin_amdgcn_mfma_f32_16x16x32_bf16(a, bW11,  ah1, 0, 0, 0);
    ai  = __builtin_amdgcn_mfma_f32_16x16x32_bf16(a, bWi,   ai,  0, 0, 0);

    float t0 = fmaxf(am0[0], 0.f) * wm2a + fmaxf(am1[0], 0.f) * wm2b;
    float t1 = fmaxf(am0[1], 0.f) * wm2a + fmaxf(am1[1], 0.f) * wm2b;
    float t2 = fmaxf(am0[2], 0.f) * wm2a + fmaxf(am1[2], 0.f) * wm2b;
    float t3 = fmaxf(am0[3], 0.f) * wm2a + fmaxf(am1[3], 0.f) * wm2b;
    t0 = red16(t0); t1 = red16(t1); t2 = red16(t2); t3 = red16(t3);

    if (p0 + 16 <= n) {
      if (nn == 15) {
        *reinterpret_cast<float4*>(mask_out + p0 + grp * 4) =
            make_float4(t0 + bm2v, t1 + bm2v, t2 + bm2v, t3 + bm2v);
      }
      if (nn == 0) {
        *reinterpret_cast<float4*>(iou_out + p0 + grp * 4) =
            make_float4(ai[0] + biv, ai[1] + biv, ai[2] + biv, ai[3] + biv);
      }
    } else {
      if (nn == 15) {
        float tv[4] = {t0, t1, t2, t3};
#pragma unroll
        for (int r = 0; r < 4; r++) {
          int p = p0 + grp * 4 + r;
          if (p < n) mask_out[p] = tv[r] + bm2v;
        }
      }
      if (nn == 0) {
#pragma unroll
        for (int r = 0; r < 4; r++) {
          int p = p0 + grp * 4 + r;
          if (p < n) iou_out[p] = ai[r] + biv;
        }
      }
    }

#pragma unroll
    for (int r = 0; r < 4; r++) {
      hs0 += ah0[r]; hq0 = fmaf(ah0[r], ah0[r], hq0);
      hs1 += ah1[r]; hq1 = fmaf(ah1[r], ah1[r], hq1);
    }
  }

  __syncthreads();
  for (int q = t; q < 64; q += 256) red[q] = 0.f;
  __syncthreads();
  lds_addf(&red[nn], hs0);       lds_addf(&red[nn + 16], hs1);
  lds_addf(&red[32 + nn], hq0);  lds_addf(&red[48 + nn], hq1);
  __syncthreads();
  for (int q = t; q < 64; q += 256) glb_addf(&stats[q], red[q]);
}

// ================= kernels =================

__global__ void k_zero(float* __restrict__ head, int nfloats, int* __restrict__ cnt) {
  int t = blockIdx.x * blockDim.x + threadIdx.x;
  int stride = gridDim.x * blockDim.x;
  for (int i = t; i < nfloats; i += stride) head[i] = 0.f;
  for (int i = t; i < PPROP; i += stride) cnt[i] = 0;
}

// phase 1: STRIPED scores/group, period {S,S,G} (round-12 lesson: contiguous
// role ranges serialize — long-running grid-stride scores blocks fill all
// resident slots first and group blocks queue behind them; striping keeps the
// resident mix at the intended 2:1 at all times)
__global__ __launch_bounds__(256, 4) void k_p1(
    const float* __restrict__ sem, const float* __restrict__ bin,
    float* __restrict__ out, int4* __restrict__ packed, int n,
    const int* __restrict__ pidx, const int* __restrict__ pid,
    int* __restrict__ cnt, int* __restrict__ bucket, int m) {
  int bid = blockIdx.x;
  int r = bid % 3, b3 = bid / 3;   // grid = 3072: 2048 scores + 1024 group
  if (r < 2) {
    dev_scores(b3 * 2 + r, 2048, sem, bin, out, packed, n);
  } else {
    dev_group(b3, pidx, pid, cnt, bucket, m);
  }
}

// phase 2: STRIPED psum/heads, period {P,H,H}
__global__ __launch_bounds__(256, 4) void k_p2(
    const int4* __restrict__ packed, const int* __restrict__ cnt,
    const int* __restrict__ bucket, float* __restrict__ psem,
    float* __restrict__ pbin,
    const float* __restrict__ feats, const float* __restrict__ W1,
    const float* __restrict__ Wm1, const float* __restrict__ bm1,
    const float* __restrict__ Wm2, const float* __restrict__ bm2,
    const float* __restrict__ Wi,  const float* __restrict__ bi,
    float* __restrict__ mask_out, float* __restrict__ iou_out,
    float* __restrict__ stats, int n) {
  int bid = blockIdx.x;
  int r = bid % 3, b3 = bid / 3;   // grid = 3072: 1024 psum + 2048 heads
  if (r == 0) {
    dev_psum(b3, packed, cnt, bucket, psem, pbin);
  } else {
    int hb_idx = b3 * 2 + (r - 1);
    int wave = (hb_idx * 256 + threadIdx.x) >> 6;
    dev_heads(wave, 2048 * 4, feats, W1, Wm1, bm1, Wm2, bm2, Wi, bi,
              mask_out, iou_out, stats, n);
  }
}

// ---- fallback standalone kernels (ws too small for grouped path) ----
__global__ void k_scores_s(const float* __restrict__ sem, const float* __restrict__ bin,
                           float* __restrict__ out, int4* __restrict__ packed, int n) {
  dev_scores(blockIdx.x, gridDim.x, sem, bin, out, packed, n);
}

__global__ __launch_bounds__(256, 4) void k_heads_s(const float* __restrict__ feats,
    const float* __restrict__ W1,
    const float* __restrict__ Wm1, const float* __restrict__ bm1,
    const float* __restrict__ Wm2, const float* __restrict__ bm2,
    const float* __restrict__ Wi,  const float* __restrict__ bi,
    float* __restrict__ mask_out, float* __restrict__ iou_out,
    float* __restrict__ stats, int n) {
  int wave = (blockIdx.x * 256 + threadIdx.x) >> 6;
  dev_heads(wave, gridDim.x * 4, feats, W1, Wm1, bm1, Wm2, bm2, Wi, bi,
            mask_out, iou_out, stats, n);
}

__global__ __launch_bounds__(512) void k_scatter_p(const int4* __restrict__ packed,
    const int* __restrict__ pidx, const int* __restrict__ pid,
    float* __restrict__ acc, int m) {
  __shared__ float tbl[PPROP * TBLW];
  for (int t = threadIdx.x; t < PPROP * TBLW; t += blockDim.x) tbl[t] = 0.f;
  __syncthreads();
  int stride = gridDim.x * blockDim.x;
  for (int i = blockIdx.x * blockDim.x + threadIdx.x; i < m; i += stride) {
    int q = pidx[i];
    int p = pid[i];
    const int4* r = packed + (size_t)q * 3;
    int4 a = r[0], b = r[1], c = r[2];
    float* t = tbl + p * TBLW;
    lds_addf(t + 0, bflo(a.x)); lds_addf(t + 1, bfhi(a.x));
    lds_addf(t + 2, bflo(a.y)); lds_addf(t + 3, bfhi(a.y));
    lds_addf(t + 4, bflo(a.z)); lds_addf(t + 5, bfhi(a.z));
    lds_addf(t + 6, bflo(a.w)); lds_addf(t + 7, bfhi(a.w));
    lds_addf(t + 8, bflo(b.x)); lds_addf(t + 9, bfhi(b.x));
    lds_addf(t +10, bflo(b.y)); lds_addf(t +11, bfhi(b.y));
    lds_addf(t +12, bflo(b.z)); lds_addf(t +13, bfhi(b.z));
    lds_addf(t +14, bflo(b.w)); lds_addf(t +15, bfhi(b.w));
    lds_addf(t +16, bflo(c.x)); lds_addf(t +17, bfhi(c.x));
    lds_addf(t +18, bflo(c.y));
    lds_addf(t +19, 1.f);
  }
  __syncthreads();
  for (int t = threadIdx.x; t < PPROP * TBLW; t += blockDim.x) {
    float v = tbl[t];
    if (v != 0.f) glb_addf(acc + t, v);
  }
}

__global__ __launch_bounds__(512) void k_scatter(const float* __restrict__ sem,
    const float* __restrict__ bin, const int* __restrict__ pidx,
    const int* __restrict__ pid, float* __restrict__ acc, int m) {
  __shared__ float tbl[PPROP * TBLW];
  for (int t = threadIdx.x; t < PPROP * TBLW; t += blockDim.x) tbl[t] = 0.f;
  __syncthreads();
  int stride = gridDim.x * blockDim.x;
  for (int i = blockIdx.x * blockDim.x + threadIdx.x; i < m; i += stride) {
    int q = pidx[i];
    int p = pid[i];
    const float* row = sem + (size_t)q * KCLS;
    float2 a  = *reinterpret_cast<const float2*>(row + 2);
    float4 c0 = *reinterpret_cast<const float4*>(row + 4);
    float4 c1 = *reinterpret_cast<const float4*>(row + 8);
    float4 c2 = *reinterpret_cast<const float4*>(row + 12);
    float4 c3 = *reinterpret_cast<const float4*>(row + 16);
    float bv = bin[q];
    float* t = tbl + p * TBLW;
    lds_addf(t + 0, a.x);  lds_addf(t + 1, a.y);
    lds_addf(t + 2, c0.x); lds_addf(t + 3, c0.y); lds_addf(t + 4, c0.z); lds_addf(t + 5, c0.w);
    lds_addf(t + 6, c1.x); lds_addf(t + 7, c1.y); lds_addf(t + 8, c1.z); lds_addf(t + 9, c1.w);
    lds_addf(t +10, c2.x); lds_addf(t +11, c2.y); lds_addf(t +12, c2.z); lds_addf(t +13, c2.w);
    lds_addf(t +14, c3.x); lds_addf(t +15, c3.y); lds_addf(t +16, c3.z); lds_addf(t +17, c3.w);
    lds_addf(t +18, bv);
    lds_addf(t +19, 1.f);
  }
  __syncthreads();
  for (int t = threadIdx.x; t < PPROP * TBLW; t += blockDim.x) {
    float v = tbl[t];
    if (v != 0.f) glb_addf(acc + t, v);
  }
}

__global__ void k_finalize(const float* __restrict__ acc,
                           float* __restrict__ psem, float* __restrict__ pbin) {
  int p = blockIdx.x * blockDim.x + threadIdx.x;
  if (p < PPROP) {
    const float* t = acc + p * TBLW;
    float cnt = fmaxf(t[19], 1.f);
    float r = 1.f / cnt;
#pragma unroll
    for (int c = 0; c < 18; c++) psem[p * 18 + c] = t[c] * r;
    pbin[p] = t[18] * r;
  }
}

// ---------------- pt_offsets via MFMA, BN prep inlined ----------------
// stats hold S=sum(f@W1), Q=sum((f@W1)^2); var shift-invariant so b1 cancels;
// tc = be1 - mean*sc makes (h_noBias*sc + tc) == BN(h_full).
__global__ __launch_bounds__(256, 4) void k_offsets_m(const float* __restrict__ feats,
    const float* __restrict__ W1,
    const float* __restrict__ W2, const float* __restrict__ b2,
    const float* __restrict__ stats, const float* __restrict__ g1,
    const float* __restrict__ be1, float* __restrict__ out_off, int n, float invN) {
  int t = threadIdx.x;
  int lane = t & 63;
  int nn = lane & 15;
  int grp = lane >> 4;

  bf16x8 bW10 = make_bfrag(W1, lane, 0);
  bf16x8 bW11 = make_bfrag(W1, lane, 16);
  float scA, tcA, scB, tcB;
  {
    float meanA = stats[nn] * invN;
    float varA  = stats[CDIM + nn] * invN - meanA * meanA;
    scA = g1[nn] * rsqrtf(varA + 1e-4f);
    tcA = be1[nn] - meanA * scA;
    float meanB = stats[nn + 16] * invN;
    float varB  = stats[CDIM + nn + 16] * invN - meanB * meanB;
    scB = g1[nn + 16] * rsqrtf(varB + 1e-4f);
    tcB = be1[nn + 16] - meanB * scB;
  }
  float wxA = W2[nn * 3 + 0], wxB = W2[(nn + 16) * 3 + 0];
  float wyA = W2[nn * 3 + 1], wyB = W2[(nn + 16) * 3 + 1];
  float wzA = W2[nn * 3 + 2], wzB = W2[(nn + 16) * 3 + 2];
  float b2x = b2[0], b2y = b2[1], b2z = b2[2];

  int wave   = (blockIdx.x * blockDim.x + t) >> 6;
  int nwaves = (gridDim.x * blockDim.x) >> 6;
  int ntiles = (n + 15) >> 4;

  for (int tile = wave; tile < ntiles; tile += nwaves) {
    int p0 = tile << 4;
    int row = p0 + nn;
    bool rv = row < n;
    const float4* fr = reinterpret_cast<const float4*>(
        feats + (size_t)(rv ? row : (n - 1)) * CDIM + grp * 8);
    float4 v0 = fr[0], v1 = fr[1];
    bf16x8 a;
    if (rv) {
      a[0] = f2bf(v0.x); a[1] = f2bf(v0.y); a[2] = f2bf(v0.z); a[3] = f2bf(v0.w);
      a[4] = f2bf(v1.x); a[5] = f2bf(v1.y); a[6] = f2bf(v1.z); a[7] = f2bf(v1.w);
    } else {
#pragma unroll
      for (int e = 0; e < 8; e++) a[e] = 0;
    }

    f32x4 ah0 = {0.f, 0.f, 0.f, 0.f}, ah1 = {0.f, 0.f, 0.f, 0.f};
    ah0 = __builtin_amdgcn_mfma_f32_16x16x32_bf16(a, bW10, ah0, 0, 0, 0);
    ah1 = __builtin_amdgcn_mfma_f32_16x16x32_bf16(a, bW11, ah1, 0, 0, 0);

    float tx[4], ty[4], tz[4];
#pragma unroll
    for (int r = 0; r < 4; r++) {
      float y0 = fmaxf(fmaf(ah0[r], scA, tcA), 0.f);
      float y1 = fmaxf(fmaf(ah1[r], scB, tcB), 0.f);
      tx[r] = red16(y0 * wxA + y1 * wxB);
      ty[r] = red16(y0 * wyA + y1 * wyB);
      tz[r] = red16(y0 * wzA + y1 * wzB);
    }

    if (nn == 15) {
      int pbase = p0 + grp * 4;
      if (pbase + 4 <= n) {
        float4* o = reinterpret_cast<float4*>(out_off + (size_t)pbase * 3);
        o[0] = make_float4(tx[0] + b2x, ty[0] + b2y, tz[0] + b2z, tx[1] + b2x);
        o[1] = make_float4(ty[1] + b2y, tz[1] + b2z, tx[2] + b2x, ty[2] + b2y);
        o[2] = make_float4(tz[2] + b2z, tx[3] + b2x, ty[3] + b2y, tz[3] + b2z);
      } else {
#pragma unroll
        for (int r = 0; r < 4; r++) {
          int p = pbase + r;
          if (p < n) {
            out_off[(size_t)p * 3 + 0] = tx[r] + b2x;
            out_off[(size_t)p * 3 + 1] = ty[r] + b2y;
            out_off[(size_t)p * 3 + 2] = tz[r] + b2z;
          }
        }
      }
    }
  }
}

extern "C" void kernel_launch(void* const* d_in, const int* in_sizes, int n_in,
                              void* d_out, int out_size, void* d_ws, size_t ws_size,
                              hipStream_t stream) {
  const float* feats = (const float*)d_in[0];
  const float* sem   = (const float*)d_in[1];
  const float* bin   = (const float*)d_in[2];
  const int*   pidx  = (const int*)d_in[3];
  const int*   pid   = (const int*)d_in[4];
  const float* W1  = (const float*)d_in[5];
  // b1 (d_in[6]) cancels analytically: BN var is shift-invariant, mean shift folds
  const float* g1  = (const float*)d_in[7];
  const float* be1 = (const float*)d_in[8];
  const float* W2  = (const float*)d_in[9];
  const float* b2  = (const float*)d_in[10];
  const float* Wm1 = (const float*)d_in[11];
  const float* bm1 = (const float*)d_in[12];
  const float* Wm2 = (const float*)d_in[13];
  const float* bm2 = (const float*)d_in[14];
  const float* Wi  = (const float*)d_in[15];
  const float* bi  = (const float*)d_in[16];

  int n = in_sizes[2];   // binary_scores is (N,1)
  int m = in_sizes[3];   // memberships

  float* out = (float*)d_out;
  float* o_scores = out;
  float* o_off  = out + (size_t)n * KCLS;
  float* o_psem = o_off + (size_t)n * 3;
  float* o_pbin = o_psem + (size_t)PPROP * 18;
  float* o_mask = o_pbin + PPROP;
  float* o_iou  = o_mask + n;

  char* wsb = (char*)d_ws;
  float* stats = (float*)wsb;               // 64 floats: S[32], Q[32]
  float* acc   = stats + 2 * CDIM;          // P*TBLW floats (fallback paths)
  size_t head_floats = 2 * CDIM + PPROP * TBLW;
  int* cnt = (int*)(wsb + head_floats * sizeof(float));   // 1024 ints
  size_t pk_off = (head_floats * sizeof(float) + PPROP * sizeof(int) + 15) & ~(size_t)15;
  size_t pk_bytes = (size_t)n * PKW * sizeof(short);      // 16B multiple
  size_t bk_off = pk_off + pk_bytes;
  size_t bk_bytes = (size_t)PPROP * SLOTS * sizeof(int);
  bool use_packed  = (pk_off + pk_bytes) <= ws_size;
  bool use_grouped = use_packed && (bk_off + bk_bytes) <= ws_size;
  int4* packed = use_packed ? (int4*)(wsb + pk_off) : nullptr;
  int* bucket  = (int*)(wsb + bk_off);

  if (use_grouped) {
    // m must fit 1024 group blocks x 2048 memberships; else fall through below
    if (m <= 1024 * 2048) {
      k_zero<<<2, 256, 0, stream>>>(stats, 2 * CDIM, cnt);
      k_p1<<<3072, 256, 0, stream>>>(sem, bin, o_scores, packed, n,
                                     pidx, pid, cnt, bucket, m);
      k_p2<<<3072, 256, 0, stream>>>(packed, cnt, bucket, o_psem, o_pbin,
                                     feats, W1, Wm1, bm1, Wm2, bm2, Wi, bi,
                                     o_mask, o_iou, stats, n);
      k_offsets_m<<<2048, 256, 0, stream>>>(feats, W1, W2, b2, stats, g1, be1,
                                            o_off, n, 1.0f / (float)n);
      return;
    }
  }
  k_zero<<<32, 256, 0, stream>>>(stats, (int)head_floats, cnt);
  k_scores_s<<<2048, 256, 0, stream>>>(sem, bin, o_scores, packed, n);
  if (use_packed) {
    k_scatter_p<<<512, 512, 0, stream>>>(packed, pidx, pid, acc, m);
  } else {
    k_scatter <<<512, 512, 0, stream>>>(sem, bin, pidx, pid, acc, m);
  }
  k_finalize<<<4, 256, 0, stream>>>(acc, o_psem, o_pbin);
  k_heads_s<<<2048, 256, 0, stream>>>(feats, W1, Wm1, bm1, Wm2, bm2, Wi, bi,
                                      o_mask, o_iou, stats, n);
  k_offsets_m<<<2048, 256, 0, stream>>>(feats, W1, W2, b2, stats, g1, be1,
                                        o_off, n, 1.0f / (float)n);
}